// Round 6
// baseline (411.698 us; speedup 1.0000x reference)
//
#include <hip/hip_runtime.h>

#define F_IN 256
#define SC_CHUNK 4096

typedef short bf8_t __attribute__((ext_vector_type(8)));   // 8 bf16
typedef float f4_t  __attribute__((ext_vector_type(4)));   // 4 fp32 acc

__device__ __forceinline__ unsigned short f2bf(float f) {
  unsigned u = __float_as_uint(f);
  unsigned r = (u + 0x7FFFu + ((u >> 16) & 1u)) >> 16;  // RNE
  return (unsigned short)r;
}
#define BF_LO(d) __uint_as_float((d) << 16)
#define BF_HI(d) __uint_as_float((d) & 0xFFFF0000u)

// ------- MFMA GEMM: hb = bf16(dinv[row] * (x @ W))  (M x 256)@(256 x 64) -----
// block = 256 thr (4 waves), 128 rows/block. Wave w: rows w*32..w*32+31,
// all 64 cols => acc[2][4] tiles of 16x16. K staged in LDS as bf16.
__global__ __launch_bounds__(256) void gemm_mfma_kernel(
    const float* __restrict__ x, const float* __restrict__ W,
    const float* __restrict__ dinvp, unsigned short* __restrict__ hb, int M) {
  __shared__ short As[128][40];    // [row][k] bf16, stride 40 (80 B, 16B-aligned)
  __shared__ short Bs[64][264];    // [n][k]  bf16, stride 264 (528 B, 16B-aligned)
  const int t = threadIdx.x;
  const int brow = blockIdx.x * 128;
  const int w = t >> 6;
  const int l = t & 63;
  const int mlane = l & 15;
  const int quad = l >> 4;

  // stage all of W (256x64) once: Bs[n][k] = bf16(W[k][n])
  for (int i = 0; i < 64; ++i) {
    const int flat = i * 256 + t;          // coalesced over t
    const int k = flat >> 6, n = flat & 63;
    Bs[n][k] = (short)f2bf(W[flat]);
  }

  f4_t acc[2][4];
#pragma unroll
  for (int a = 0; a < 2; ++a)
#pragma unroll
    for (int b = 0; b < 4; ++b) acc[a][b] = (f4_t){0.f, 0.f, 0.f, 0.f};

  for (int k0 = 0; k0 < F_IN; k0 += 32) {
    // stage A tile: As[r][c] = bf16(x[brow+r][k0+c]), r<128, c<32
    {
      const int q = t & 7;          // 8 float4 per row of 32
      const int rbase = t >> 3;     // 32 rows per pass
#pragma unroll
      for (int j = 0; j < 4; ++j) {
        const int r = rbase + j * 32;
        const int row = brow + r;
        float4 v = make_float4(0.f, 0.f, 0.f, 0.f);
        if (row < M) v = *(const float4*)(x + (size_t)row * F_IN + k0 + (q << 2));
        short* p = &As[r][q << 2];
        p[0] = (short)f2bf(v.x);
        p[1] = (short)f2bf(v.y);
        p[2] = (short)f2bf(v.z);
        p[3] = (short)f2bf(v.w);
      }
    }
    __syncthreads();
    bf8_t afr[2], bfr[4];
#pragma unroll
    for (int mt = 0; mt < 2; ++mt)
      afr[mt] = *(const bf8_t*)&As[w * 32 + mt * 16 + mlane][quad << 3];
#pragma unroll
    for (int nt = 0; nt < 4; ++nt)
      bfr[nt] = *(const bf8_t*)&Bs[nt * 16 + mlane][k0 + (quad << 3)];
#pragma unroll
    for (int mt = 0; mt < 2; ++mt)
#pragma unroll
      for (int nt = 0; nt < 4; ++nt)
        acc[mt][nt] = __builtin_amdgcn_mfma_f32_16x16x32_bf16(
            afr[mt], bfr[nt], acc[mt][nt], 0, 0, 0);
    __syncthreads();
  }

  // epilogue: D row = quad*4+reg (in m-tile), col = mlane (in n-tile)
#pragma unroll
  for (int mt = 0; mt < 2; ++mt) {
#pragma unroll
    for (int reg = 0; reg < 4; ++reg) {
      const int row = brow + w * 32 + mt * 16 + (quad << 2) + reg;
      if (row < M) {
        const float di = dinvp[row];
#pragma unroll
        for (int nt = 0; nt < 4; ++nt)
          hb[(size_t)row * 64 + nt * 16 + mlane] = f2bf(di * acc[mt][nt][reg]);
      }
    }
  }
}

// ---------------- coarse histogram over dst>>8 -------------------------------
__global__ __launch_bounds__(256) void hist_coarse_kernel(
    const int* __restrict__ dst_arr, int* __restrict__ bucketCount,
    int E, int NBK) {
  __shared__ int hist[512];
  const int t = threadIdx.x;
  for (int i = t; i < NBK; i += 256) hist[i] = 0;
  __syncthreads();
  const int base = blockIdx.x * SC_CHUNK;
  const int end = min(base + SC_CHUNK, E);
  for (int i = base + t; i < end; i += 256)
    atomicAdd(&hist[dst_arr[i] >> 8], 1);
  __syncthreads();
  for (int i = t; i < NBK; i += 256)
    if (hist[i]) atomicAdd(&bucketCount[i], hist[i]);
}

// ---------------- scan bucket counts (NBK <= 512) ----------------------------
__global__ __launch_bounds__(512) void scan_buckets_kernel(
    const int* __restrict__ bucketCount, int* __restrict__ bucketStart,
    int* __restrict__ bucketCursor, int NBK) {
  __shared__ int s[512];
  const int t = threadIdx.x;
  const int v = (t < NBK) ? bucketCount[t] : 0;
  s[t] = v;
  __syncthreads();
#pragma unroll
  for (int off = 1; off < 512; off <<= 1) {
    int add = (t >= off) ? s[t - off] : 0;
    __syncthreads();
    s[t] += add;
    __syncthreads();
  }
  if (t < NBK) {
    const int excl = s[t] - v;
    bucketStart[t] = excl;
    bucketCursor[t] = excl;
  }
  if (t == NBK - 1) bucketStart[NBK] = s[t];
}

// ------- coarse scatter: esp grouped by bucket, packed src|(dst&255)<<24 -----
__global__ __launch_bounds__(256) void scatter_coarse_kernel(
    const int* __restrict__ src_arr, const int* __restrict__ dst_arr,
    int* __restrict__ bucketCursor, int* __restrict__ esp, int E, int NBK) {
  __shared__ int hist[512];
  __shared__ int cur[512];
  const int t = threadIdx.x;
  for (int i = t; i < NBK; i += 256) hist[i] = 0;
  __syncthreads();
  const int base = blockIdx.x * SC_CHUNK;
  const int end = min(base + SC_CHUNK, E);
  for (int i = base + t; i < end; i += 256)
    atomicAdd(&hist[dst_arr[i] >> 8], 1);
  __syncthreads();
  for (int i = t; i < NBK; i += 256)
    cur[i] = hist[i] ? atomicAdd(&bucketCursor[i], hist[i]) : 0;
  __syncthreads();
  for (int i = base + t; i < end; i += 256) {
    const int s = src_arr[i];
    const int d = dst_arr[i];
    const int pos = atomicAdd(&cur[d >> 8], 1);
    esp[pos] = s | ((d & 255) << 24);
  }
}

// ------ per-bucket fine bin: CSR rowptr + sorted es + dinvp ------------------
__global__ __launch_bounds__(512) void fine_bin_kernel(
    const int* __restrict__ esp, const int* __restrict__ bucketStart,
    int* __restrict__ es, int* __restrict__ rowptr, float* __restrict__ dinvp,
    int N, int E) {
  __shared__ int hist[256];
  __shared__ int s[256];
  __shared__ int cur[256];
  const int t = threadIdx.x;
  if (t < 256) hist[t] = 0;
  __syncthreads();
  const int b = blockIdx.x;
  const int start = bucketStart[b], end = bucketStart[b + 1];
  for (int i = start + t; i < end; i += 512)
    atomicAdd(&hist[((unsigned)esp[i]) >> 24], 1);
  __syncthreads();
  int v = 0;
  if (t < 256) { v = hist[t]; s[t] = v; }
  __syncthreads();
#pragma unroll
  for (int off = 1; off < 256; off <<= 1) {
    int add = 0;
    if (t < 256 && t >= off) add = s[t - off];
    __syncthreads();
    if (t < 256) s[t] += add;
    __syncthreads();
  }
  if (t < 256) {
    const int excl = s[t] - v;
    cur[t] = start + excl;
    const int node = b * 256 + t;
    if (node < N) {
      rowptr[node] = start + excl;
      dinvp[node] = rsqrtf((float)(v + 1));  // +1 self-loop
    }
    if (b == gridDim.x - 1 && t == 255) rowptr[N] = E;
  }
  __syncthreads();
  for (int i = start + t; i < end; i += 512) {
    const int p = esp[i];
    const int pos = atomicAdd(&cur[((unsigned)p) >> 24], 1);
    es[pos] = p & 0x00FFFFFF;
  }
}

// ------- CSR aggregation: one wave per node, bf16 pre-scaled gather ----------
__global__ __launch_bounds__(256) void agg_csr_kernel(
    const unsigned short* __restrict__ hb, const int* __restrict__ es,
    const int* __restrict__ rowptr, const float* __restrict__ dinvp,
    float* __restrict__ agg, int N) {
  const int t = threadIdx.x;
  const int node = blockIdx.x * 4 + (t >> 6);
  if (node >= N) return;
  const int lane = t & 63;
  const int slot = lane >> 3;        // 0..7 : edge slot
  const int fq = (lane & 7) << 3;    // feature base (8 feats, 16 B)
  const int start = rowptr[node];
  const int end = rowptr[node + 1];

  float acc[8] = {0.f};
  int i = start + slot;
  for (; i + 8 < end; i += 16) {
    const int s0 = es[i];
    const int s1 = es[i + 8];
    const uint4 r0 = *(const uint4*)(hb + (size_t)s0 * 64 + fq);
    const uint4 r1 = *(const uint4*)(hb + (size_t)s1 * 64 + fq);
    acc[0] += BF_LO(r0.x) + BF_LO(r1.x);
    acc[1] += BF_HI(r0.x) + BF_HI(r1.x);
    acc[2] += BF_LO(r0.y) + BF_LO(r1.y);
    acc[3] += BF_HI(r0.y) + BF_HI(r1.y);
    acc[4] += BF_LO(r0.z) + BF_LO(r1.z);
    acc[5] += BF_HI(r0.z) + BF_HI(r1.z);
    acc[6] += BF_LO(r0.w) + BF_LO(r1.w);
    acc[7] += BF_HI(r0.w) + BF_HI(r1.w);
  }
  if (i < end) {
    const int s0 = es[i];
    const uint4 r0 = *(const uint4*)(hb + (size_t)s0 * 64 + fq);
    acc[0] += BF_LO(r0.x);
    acc[1] += BF_HI(r0.x);
    acc[2] += BF_LO(r0.y);
    acc[3] += BF_HI(r0.y);
    acc[4] += BF_LO(r0.z);
    acc[5] += BF_HI(r0.z);
    acc[6] += BF_LO(r0.w);
    acc[7] += BF_HI(r0.w);
  }
#pragma unroll
  for (int m = 8; m <= 32; m <<= 1)
#pragma unroll
    for (int j = 0; j < 8; ++j) acc[j] += __shfl_xor(acc[j], m, 64);

  if (slot == 0) {
    const float di = dinvp[node];
    float4 o0 = make_float4(acc[0] * di, acc[1] * di, acc[2] * di, acc[3] * di);
    float4 o1 = make_float4(acc[4] * di, acc[5] * di, acc[6] * di, acc[7] * di);
    float* ap = agg + (size_t)node * 64 + fq;
    *(float4*)(ap + 0) = o0;
    *(float4*)(ap + 4) = o1;
  }
}

// ---------------- fused epilogue + MLP ---------------------------------------
__global__ __launch_bounds__(256) void mlp_kernel(
    const float* __restrict__ agg, const unsigned short* __restrict__ hb,
    const float* __restrict__ dinvp, const float* __restrict__ bg,
    const float* __restrict__ W1, const float* __restrict__ b1,
    const float* __restrict__ W2, const float* __restrict__ b2,
    const float* __restrict__ W3, const float* __restrict__ b3,
    float* __restrict__ out, int N) {
  __shared__ float W1T[32][64];
  __shared__ float W2T[16][32];
  __shared__ float W3T[10][16];
  __shared__ float b1s[32], b2s[16], b3s[10], bgs[64];
  const int t = threadIdx.x;
  for (int i = t; i < 2048; i += 256) W1T[i >> 6][i & 63] = W1[(i & 63) * 32 + (i >> 6)];
  for (int i = t; i < 512; i += 256)  W2T[i >> 5][i & 31] = W2[(i & 31) * 16 + (i >> 5)];
  for (int i = t; i < 160; i += 256)  W3T[i >> 4][i & 15] = W3[(i & 15) * 10 + (i >> 4)];
  if (t < 64) bgs[t] = bg[t];
  if (t < 32) b1s[t] = b1[t];
  if (t < 16) b2s[t] = b2[t];
  if (t < 10) b3s[t] = b3[t];
  __syncthreads();

  const int node = blockIdx.x * 256 + t;
  if (node >= N) return;
  const float di = dinvp[node];

  float g[64];
#pragma unroll
  for (int k = 0; k < 64; k += 8) {
    const float4 a0 = *(const float4*)(agg + (size_t)node * 64 + k);
    const float4 a1 = *(const float4*)(agg + (size_t)node * 64 + k + 4);
    const uint4 r = *(const uint4*)(hb + (size_t)node * 64 + k);
    g[k + 0] = fmaxf(a0.x + di * BF_LO(r.x) + bgs[k + 0], 0.f);
    g[k + 1] = fmaxf(a0.y + di * BF_HI(r.x) + bgs[k + 1], 0.f);
    g[k + 2] = fmaxf(a0.z + di * BF_LO(r.y) + bgs[k + 2], 0.f);
    g[k + 3] = fmaxf(a0.w + di * BF_HI(r.y) + bgs[k + 3], 0.f);
    g[k + 4] = fmaxf(a1.x + di * BF_LO(r.z) + bgs[k + 4], 0.f);
    g[k + 5] = fmaxf(a1.y + di * BF_HI(r.z) + bgs[k + 5], 0.f);
    g[k + 6] = fmaxf(a1.z + di * BF_LO(r.w) + bgs[k + 6], 0.f);
    g[k + 7] = fmaxf(a1.w + di * BF_HI(r.w) + bgs[k + 7], 0.f);
  }

  float h1[32];
#pragma unroll
  for (int j = 0; j < 32; ++j) {
    float acc = b1s[j];
#pragma unroll
    for (int k = 0; k < 64; k += 4) {
      const float4 w = *(const float4*)&W1T[j][k];
      acc += g[k] * w.x + g[k + 1] * w.y + g[k + 2] * w.z + g[k + 3] * w.w;
    }
    h1[j] = fmaxf(acc, 0.f);
  }

  float h2[16];
#pragma unroll
  for (int j = 0; j < 16; ++j) {
    float acc = b2s[j];
#pragma unroll
    for (int k = 0; k < 32; k += 4) {
      const float4 w = *(const float4*)&W2T[j][k];
      acc += h1[k] * w.x + h1[k + 1] * w.y + h1[k + 2] * w.z + h1[k + 3] * w.w;
    }
    h2[j] = fmaxf(acc, 0.f);
  }

#pragma unroll
  for (int j = 0; j < 10; ++j) {
    float acc = b3s[j];
#pragma unroll
    for (int k = 0; k < 16; k += 4) {
      const float4 w = *(const float4*)&W3T[j][k];
      acc += h2[k] * w.x + h2[k + 1] * w.y + h2[k + 2] * w.z + h2[k + 3] * w.w;
    }
    out[(size_t)node * 10 + j] = acc;
  }
}

extern "C" void kernel_launch(void* const* d_in, const int* in_sizes, int n_in,
                              void* d_out, int out_size, void* d_ws, size_t ws_size,
                              hipStream_t stream) {
  const float* x     = (const float*)d_in[0];
  const int*   ei    = (const int*)d_in[1];
  const float* W_gcn = (const float*)d_in[2];
  const float* b_gcn = (const float*)d_in[3];
  const float* W1    = (const float*)d_in[4];
  const float* b1    = (const float*)d_in[5];
  const float* W2    = (const float*)d_in[6];
  const float* b2    = (const float*)d_in[7];
  const float* W3    = (const float*)d_in[8];
  const float* b3    = (const float*)d_in[9];
  float* out = (float*)d_out;

  const int N = in_sizes[0] / F_IN;   // 100000
  const int E = in_sizes[1] / 2;      // 3200000
  const int* src = ei;
  const int* dst = ei + E;
  const int NBK = (N + 255) >> 8;     // 391 buckets of 256 nodes
  const int NBLK_E = (E + SC_CHUNK - 1) / SC_CHUNK;

  // Layout (~52 MB): esp (E int, dead after fine_bin) aliased by agg (N*64 f).
  unsigned short* hb = (unsigned short*)d_ws;            // N*64 us  (12.8 MB)
  float* dinvp       = (float*)(hb + (size_t)N * 64);    // N f
  int*   es          = (int*)(dinvp + N);                // E i      (12.8 MB)
  int*   rowptr      = es + E;                           // N+16 i
  int*   bucketCount = rowptr + N + 16;                  // 512 i
  int*   bucketStart = bucketCount + 512;                // 528 i
  int*   bucketCursor= bucketStart + 528;                // 512 i
  int*   esp         = bucketCursor + 512;               // E i      (12.8 MB)
  float* agg         = (float*)esp;                      // N*64 f (25.6 MB alias)

  hipMemsetAsync(bucketCount, 0, 512 * sizeof(int), stream);

  hist_coarse_kernel<<<NBLK_E, 256, 0, stream>>>(dst, bucketCount, E, NBK);
  scan_buckets_kernel<<<1, 512, 0, stream>>>(bucketCount, bucketStart, bucketCursor, NBK);
  scatter_coarse_kernel<<<NBLK_E, 256, 0, stream>>>(src, dst, bucketCursor, esp, E, NBK);
  fine_bin_kernel<<<NBK, 512, 0, stream>>>(esp, bucketStart, es, rowptr, dinvp, N, E);

  gemm_mfma_kernel<<<(N + 127) / 128, 256, 0, stream>>>(x, W_gcn, dinvp, hb, N);

  agg_csr_kernel<<<(N + 3) / 4, 256, 0, stream>>>(hb, es, rowptr, dinvp, agg, N);

  mlp_kernel<<<(N + 255) / 256, 256, 0, stream>>>(
      agg, hb, dinvp, b_gcn, W1, b1, W2, b2, W3, b3, out, N);
}

// Round 7
// 367.924 us; speedup vs baseline: 1.1190x; 1.1190x over previous
//
#include <hip/hip_runtime.h>

#define F_IN 256
#define CHUNK 8192
#define PMAX 24

typedef short bf8_t __attribute__((ext_vector_type(8)));   // 8 bf16
typedef float f4_t  __attribute__((ext_vector_type(4)));   // 4 fp32 acc

__device__ __forceinline__ unsigned short f2bf(float f) {
  unsigned u = __float_as_uint(f);
  unsigned r = (u + 0x7FFFu + ((u >> 16) & 1u)) >> 16;  // RNE
  return (unsigned short)r;
}
#define BF_LO(d) __uint_as_float((d) << 16)
#define BF_HI(d) __uint_as_float((d) & 0xFFFF0000u)

// ------- MFMA GEMM: hb = bf16(dinv[row] * (x @ W))  (M x 256)@(256 x 64) -----
__global__ __launch_bounds__(256) void gemm_mfma_kernel(
    const float* __restrict__ x, const float* __restrict__ W,
    const float* __restrict__ dinvp, unsigned short* __restrict__ hb, int M) {
  __shared__ short As[128][40];
  __shared__ short Bs[64][264];
  const int t = threadIdx.x;
  const int brow = blockIdx.x * 128;
  const int w = t >> 6;
  const int l = t & 63;
  const int mlane = l & 15;
  const int quad = l >> 4;

  for (int i = 0; i < 64; ++i) {
    const int flat = i * 256 + t;
    const int k = flat >> 6, n = flat & 63;
    Bs[n][k] = (short)f2bf(W[flat]);
  }

  f4_t acc[2][4];
#pragma unroll
  for (int a = 0; a < 2; ++a)
#pragma unroll
    for (int b = 0; b < 4; ++b) acc[a][b] = (f4_t){0.f, 0.f, 0.f, 0.f};

  for (int k0 = 0; k0 < F_IN; k0 += 32) {
    {
      const int q = t & 7;
      const int rbase = t >> 3;
#pragma unroll
      for (int j = 0; j < 4; ++j) {
        const int r = rbase + j * 32;
        const int row = brow + r;
        float4 v = make_float4(0.f, 0.f, 0.f, 0.f);
        if (row < M) v = *(const float4*)(x + (size_t)row * F_IN + k0 + (q << 2));
        short* p = &As[r][q << 2];
        p[0] = (short)f2bf(v.x);
        p[1] = (short)f2bf(v.y);
        p[2] = (short)f2bf(v.z);
        p[3] = (short)f2bf(v.w);
      }
    }
    __syncthreads();
    bf8_t afr[2], bfr[4];
#pragma unroll
    for (int mt = 0; mt < 2; ++mt)
      afr[mt] = *(const bf8_t*)&As[w * 32 + mt * 16 + mlane][quad << 3];
#pragma unroll
    for (int nt = 0; nt < 4; ++nt)
      bfr[nt] = *(const bf8_t*)&Bs[nt * 16 + mlane][k0 + (quad << 3)];
#pragma unroll
    for (int mt = 0; mt < 2; ++mt)
#pragma unroll
      for (int nt = 0; nt < 4; ++nt)
        acc[mt][nt] = __builtin_amdgcn_mfma_f32_16x16x32_bf16(
            afr[mt], bfr[nt], acc[mt][nt], 0, 0, 0);
    __syncthreads();
  }

#pragma unroll
  for (int mt = 0; mt < 2; ++mt) {
#pragma unroll
    for (int reg = 0; reg < 4; ++reg) {
      const int row = brow + w * 32 + mt * 16 + (quad << 2) + reg;
      if (row < M) {
        const float di = dinvp[row];
#pragma unroll
        for (int nt = 0; nt < 4; ++nt)
          hb[(size_t)row * 64 + nt * 16 + mlane] = f2bf(di * acc[mt][nt][reg]);
      }
    }
  }
}

// ------- block-local sort: each chunk sorted by bucket into own region -------
__global__ __launch_bounds__(512) void sort_local_kernel(
    const int* __restrict__ src_arr, const int* __restrict__ dst_arr,
    int* __restrict__ espB, int* __restrict__ segStart, int* __restrict__ segCnt,
    int* __restrict__ bucketCount, int E, int NBK) {
  __shared__ int hist[512];
  __shared__ int s[512];
  __shared__ int cur[512];
  const int t = threadIdx.x;
  const int blk = blockIdx.x;
  const int base = blk * CHUNK;
  const int cnt = min(CHUNK, E - base);
  for (int i = t; i < NBK; i += 512) hist[i] = 0;
  __syncthreads();
  int pk[16], bk[16];
#pragma unroll
  for (int k = 0; k < 16; ++k) {
    const int i = t + k * 512;
    bk[k] = -1;
    if (i < cnt) {
      const int sv = src_arr[base + i];
      const int dv = dst_arr[base + i];
      pk[k] = sv | ((dv & 255) << 24);
      bk[k] = dv >> 8;
      atomicAdd(&hist[bk[k]], 1);
    }
  }
  __syncthreads();
  const int v = (t < NBK) ? hist[t] : 0;
  s[t] = v;
  __syncthreads();
#pragma unroll
  for (int off = 1; off < 512; off <<= 1) {
    int add = (t >= off) ? s[t - off] : 0;
    __syncthreads();
    s[t] += add;
    __syncthreads();
  }
  if (t < NBK) {
    const int excl = s[t] - v;
    cur[t] = excl;
    segStart[blk * NBK + t] = base + excl;   // block-major: dense writes
    segCnt[blk * NBK + t] = v;
    if (v) atomicAdd(&bucketCount[t], v);
  }
  __syncthreads();
#pragma unroll
  for (int k = 0; k < 16; ++k) {
    if (bk[k] >= 0) {
      const int pos = atomicAdd(&cur[bk[k]], 1);
      espB[base + pos] = pk[k];              // dense 32 KB streaming write
    }
  }
}

// ---------------- scan bucket counts (NBK <= 512) ----------------------------
__global__ __launch_bounds__(512) void scan_buckets_kernel(
    const int* __restrict__ bucketCount, int* __restrict__ bucketStart, int NBK) {
  __shared__ int s[512];
  const int t = threadIdx.x;
  const int v = (t < NBK) ? bucketCount[t] : 0;
  s[t] = v;
  __syncthreads();
#pragma unroll
  for (int off = 1; off < 512; off <<= 1) {
    int add = (t >= off) ? s[t - off] : 0;
    __syncthreads();
    s[t] += add;
    __syncthreads();
  }
  if (t < NBK) bucketStart[t] = s[t] - v;
  if (t == NBK - 1) bucketStart[NBK] = s[t];
}

// ------ per-bucket fine bin from segments: CSR rowptr + es + dinvp -----------
__global__ __launch_bounds__(512) void fine_bin2_kernel(
    const int* __restrict__ espB, const int* __restrict__ segStart,
    const int* __restrict__ segCnt, const int* __restrict__ bucketStart,
    int* __restrict__ es, int* __restrict__ rowptr, float* __restrict__ dinvp,
    int N, int E, int NBK, int NCH) {
  __shared__ int segO[513];
  __shared__ int segS[512];
  __shared__ int s[512];
  __shared__ int hist[256];
  __shared__ int cur[256];
  const int t = threadIdx.x;
  const int b = blockIdx.x;
  int c = 0;
  if (t < NCH) {
    segS[t] = segStart[t * NBK + b];   // column read, array is L2-resident
    c = segCnt[t * NBK + b];
  }
  s[t] = c;
  if (t < 256) hist[t] = 0;
  __syncthreads();
#pragma unroll
  for (int off = 1; off < 512; off <<= 1) {
    int add = (t >= off) ? s[t - off] : 0;
    __syncthreads();
    s[t] += add;
    __syncthreads();
  }
  segO[t + 1] = s[t];
  if (t == 0) segO[0] = 0;
  __syncthreads();
  const int total = segO[NCH];
  const int base = bucketStart[b];

  int pc[PMAX];
  int it = 0;
  for (int j = t; j < total; j += 512, ++it) {
    int lo = 0, hi = NCH;
    while (hi - lo > 1) {
      const int mid = (lo + hi) >> 1;
      if (segO[mid] <= j) lo = mid; else hi = mid;
    }
    const int p = espB[segS[lo] + (j - segO[lo])];
    if (it < PMAX) pc[it] = p;
    atomicAdd(&hist[((unsigned)p) >> 24], 1);
  }
  __syncthreads();
  const int v2 = (t < 256) ? hist[t] : 0;
  s[t] = v2;
  __syncthreads();
#pragma unroll
  for (int off = 1; off < 256; off <<= 1) {
    int add = (t >= off) ? s[t - off] : 0;
    __syncthreads();
    s[t] += add;
    __syncthreads();
  }
  if (t < 256) {
    const int excl = s[t] - v2;
    cur[t] = base + excl;
    const int node = b * 256 + t;
    if (node < N) {
      rowptr[node] = base + excl;
      dinvp[node] = rsqrtf((float)(v2 + 1));  // +1 self-loop
    }
  }
  if (b == 0 && t == 0) rowptr[N] = E;
  __syncthreads();
  it = 0;
  for (int j = t; j < total; j += 512, ++it) {
    int p;
    if (it < PMAX) {
      p = pc[it];
    } else {
      int lo = 0, hi = NCH;
      while (hi - lo > 1) {
        const int mid = (lo + hi) >> 1;
        if (segO[mid] <= j) lo = mid; else hi = mid;
      }
      p = espB[segS[lo] + (j - segO[lo])];
    }
    const int pos = atomicAdd(&cur[((unsigned)p) >> 24], 1);
    es[pos] = p & 0x00FFFFFF;
  }
}

// ------- CSR aggregation: one wave per node, bf16 pre-scaled gather ----------
__global__ __launch_bounds__(256) void agg_csr_kernel(
    const unsigned short* __restrict__ hb, const int* __restrict__ es,
    const int* __restrict__ rowptr, const float* __restrict__ dinvp,
    float* __restrict__ agg, int N) {
  const int t = threadIdx.x;
  const int node = blockIdx.x * 4 + (t >> 6);
  if (node >= N) return;
  const int lane = t & 63;
  const int slot = lane >> 3;
  const int fq = (lane & 7) << 3;
  const int start = rowptr[node];
  const int end = rowptr[node + 1];

  float acc[8] = {0.f};
  int i = start + slot;
  for (; i + 8 < end; i += 16) {
    const int s0 = es[i];
    const int s1 = es[i + 8];
    const uint4 r0 = *(const uint4*)(hb + (size_t)s0 * 64 + fq);
    const uint4 r1 = *(const uint4*)(hb + (size_t)s1 * 64 + fq);
    acc[0] += BF_LO(r0.x) + BF_LO(r1.x);
    acc[1] += BF_HI(r0.x) + BF_HI(r1.x);
    acc[2] += BF_LO(r0.y) + BF_LO(r1.y);
    acc[3] += BF_HI(r0.y) + BF_HI(r1.y);
    acc[4] += BF_LO(r0.z) + BF_LO(r1.z);
    acc[5] += BF_HI(r0.z) + BF_HI(r1.z);
    acc[6] += BF_LO(r0.w) + BF_LO(r1.w);
    acc[7] += BF_HI(r0.w) + BF_HI(r1.w);
  }
  if (i < end) {
    const int s0 = es[i];
    const uint4 r0 = *(const uint4*)(hb + (size_t)s0 * 64 + fq);
    acc[0] += BF_LO(r0.x);
    acc[1] += BF_HI(r0.x);
    acc[2] += BF_LO(r0.y);
    acc[3] += BF_HI(r0.y);
    acc[4] += BF_LO(r0.z);
    acc[5] += BF_HI(r0.z);
    acc[6] += BF_LO(r0.w);
    acc[7] += BF_HI(r0.w);
  }
#pragma unroll
  for (int m = 8; m <= 32; m <<= 1)
#pragma unroll
    for (int j = 0; j < 8; ++j) acc[j] += __shfl_xor(acc[j], m, 64);

  if (slot == 0) {
    const float di = dinvp[node];
    float4 o0 = make_float4(acc[0] * di, acc[1] * di, acc[2] * di, acc[3] * di);
    float4 o1 = make_float4(acc[4] * di, acc[5] * di, acc[6] * di, acc[7] * di);
    float* ap = agg + (size_t)node * 64 + fq;
    *(float4*)(ap + 0) = o0;
    *(float4*)(ap + 4) = o1;
  }
}

// ---------------- fused epilogue + MLP ---------------------------------------
__global__ __launch_bounds__(256) void mlp_kernel(
    const float* __restrict__ agg, const unsigned short* __restrict__ hb,
    const float* __restrict__ dinvp, const float* __restrict__ bg,
    const float* __restrict__ W1, const float* __restrict__ b1,
    const float* __restrict__ W2, const float* __restrict__ b2,
    const float* __restrict__ W3, const float* __restrict__ b3,
    float* __restrict__ out, int N) {
  __shared__ float W1T[32][64];
  __shared__ float W2T[16][32];
  __shared__ float W3T[10][16];
  __shared__ float b1s[32], b2s[16], b3s[10], bgs[64];
  const int t = threadIdx.x;
  for (int i = t; i < 2048; i += 256) W1T[i >> 6][i & 63] = W1[(i & 63) * 32 + (i >> 6)];
  for (int i = t; i < 512; i += 256)  W2T[i >> 5][i & 31] = W2[(i & 31) * 16 + (i >> 5)];
  for (int i = t; i < 160; i += 256)  W3T[i >> 4][i & 15] = W3[(i & 15) * 10 + (i >> 4)];
  if (t < 64) bgs[t] = bg[t];
  if (t < 32) b1s[t] = b1[t];
  if (t < 16) b2s[t] = b2[t];
  if (t < 10) b3s[t] = b3[t];
  __syncthreads();

  const int node = blockIdx.x * 256 + t;
  if (node >= N) return;
  const float di = dinvp[node];

  float g[64];
#pragma unroll
  for (int k = 0; k < 64; k += 8) {
    const float4 a0 = *(const float4*)(agg + (size_t)node * 64 + k);
    const float4 a1 = *(const float4*)(agg + (size_t)node * 64 + k + 4);
    const uint4 r = *(const uint4*)(hb + (size_t)node * 64 + k);
    g[k + 0] = fmaxf(a0.x + di * BF_LO(r.x) + bgs[k + 0], 0.f);
    g[k + 1] = fmaxf(a0.y + di * BF_HI(r.x) + bgs[k + 1], 0.f);
    g[k + 2] = fmaxf(a0.z + di * BF_LO(r.y) + bgs[k + 2], 0.f);
    g[k + 3] = fmaxf(a0.w + di * BF_HI(r.y) + bgs[k + 3], 0.f);
    g[k + 4] = fmaxf(a1.x + di * BF_LO(r.z) + bgs[k + 4], 0.f);
    g[k + 5] = fmaxf(a1.y + di * BF_HI(r.z) + bgs[k + 5], 0.f);
    g[k + 6] = fmaxf(a1.z + di * BF_LO(r.w) + bgs[k + 6], 0.f);
    g[k + 7] = fmaxf(a1.w + di * BF_HI(r.w) + bgs[k + 7], 0.f);
  }

  float h1[32];
#pragma unroll
  for (int j = 0; j < 32; ++j) {
    float acc = b1s[j];
#pragma unroll
    for (int k = 0; k < 64; k += 4) {
      const float4 w = *(const float4*)&W1T[j][k];
      acc += g[k] * w.x + g[k + 1] * w.y + g[k + 2] * w.z + g[k + 3] * w.w;
    }
    h1[j] = fmaxf(acc, 0.f);
  }

  float h2[16];
#pragma unroll
  for (int j = 0; j < 16; ++j) {
    float acc = b2s[j];
#pragma unroll
    for (int k = 0; k < 32; k += 4) {
      const float4 w = *(const float4*)&W2T[j][k];
      acc += h1[k] * w.x + h1[k + 1] * w.y + h1[k + 2] * w.z + h1[k + 3] * w.w;
    }
    h2[j] = fmaxf(acc, 0.f);
  }

#pragma unroll
  for (int j = 0; j < 10; ++j) {
    float acc = b3s[j];
#pragma unroll
    for (int k = 0; k < 16; k += 4) {
      const float4 w = *(const float4*)&W3T[j][k];
      acc += h2[k] * w.x + h2[k + 1] * w.y + h2[k + 2] * w.z + h2[k + 3] * w.w;
    }
    out[(size_t)node * 10 + j] = acc;
  }
}

extern "C" void kernel_launch(void* const* d_in, const int* in_sizes, int n_in,
                              void* d_out, int out_size, void* d_ws, size_t ws_size,
                              hipStream_t stream) {
  const float* x     = (const float*)d_in[0];
  const int*   ei    = (const int*)d_in[1];
  const float* W_gcn = (const float*)d_in[2];
  const float* b_gcn = (const float*)d_in[3];
  const float* W1    = (const float*)d_in[4];
  const float* b1    = (const float*)d_in[5];
  const float* W2    = (const float*)d_in[6];
  const float* b2    = (const float*)d_in[7];
  const float* W3    = (const float*)d_in[8];
  const float* b3    = (const float*)d_in[9];
  float* out = (float*)d_out;

  const int N = in_sizes[0] / F_IN;   // 100000
  const int E = in_sizes[1] / 2;      // 3200000
  const int* src = ei;
  const int* dst = ei + E;
  const int NBK = (N + 255) >> 8;     // 391 buckets of 256 nodes
  const int NCH = (E + CHUNK - 1) / CHUNK;  // 391 chunks

  // Layout: espB/segStart/segCnt dead after fine_bin2 -> aliased by agg.
  unsigned short* hb = (unsigned short*)d_ws;            // N*64 us  (12.8 MB)
  float* dinvp       = (float*)(hb + (size_t)N * 64);    // N f
  int*   es          = (int*)(dinvp + N);                // E i      (12.8 MB)
  int*   rowptr      = es + E;                           // N+16 i
  int*   bucketCount = rowptr + N + 16;                  // 512 i
  int*   bucketStart = bucketCount + 512;                // 528 i
  int*   espB        = bucketStart + 528;                // E i      (12.8 MB)
  int*   segStart    = espB + E;                         // NCH*NBK i (0.61 MB)
  int*   segCnt      = segStart + NCH * NBK;             // NCH*NBK i (0.61 MB)
  float* agg         = (float*)espB;                     // N*64 f (25.6 MB alias)

  hipMemsetAsync(bucketCount, 0, 512 * sizeof(int), stream);

  sort_local_kernel<<<NCH, 512, 0, stream>>>(
      src, dst, espB, segStart, segCnt, bucketCount, E, NBK);
  scan_buckets_kernel<<<1, 512, 0, stream>>>(bucketCount, bucketStart, NBK);
  fine_bin2_kernel<<<NBK, 512, 0, stream>>>(
      espB, segStart, segCnt, bucketStart, es, rowptr, dinvp, N, E, NBK, NCH);

  gemm_mfma_kernel<<<(N + 127) / 128, 256, 0, stream>>>(x, W_gcn, dinvp, hb, N);

  agg_csr_kernel<<<(N + 3) / 4, 256, 0, stream>>>(hb, es, rowptr, dinvp, agg, N);

  mlp_kernel<<<(N + 255) / 256, 256, 0, stream>>>(
      agg, hb, dinvp, b_gcn, W1, b1, W2, b2, W3, b3, out, N);
}

// Round 8
// 360.402 us; speedup vs baseline: 1.1423x; 1.0209x over previous
//
#include <hip/hip_runtime.h>

#define F_IN 256
#define CHUNK 8192

typedef short bf8_t __attribute__((ext_vector_type(8)));   // 8 bf16
typedef float f4_t  __attribute__((ext_vector_type(4)));   // 4 fp32 acc

__device__ __forceinline__ unsigned short f2bf(float f) {
  unsigned u = __float_as_uint(f);
  unsigned r = (u + 0x7FFFu + ((u >> 16) & 1u)) >> 16;  // RNE
  return (unsigned short)r;
}
#define BF_LO(d) __uint_as_float((d) << 16)
#define BF_HI(d) __uint_as_float((d) & 0xFFFF0000u)

// ------- MFMA GEMM: hb = bf16(dinv[row] * (x @ W))  (M x 256)@(256 x 64) -----
__global__ __launch_bounds__(256) void gemm_mfma_kernel(
    const float* __restrict__ x, const float* __restrict__ W,
    const float* __restrict__ dinvp, unsigned short* __restrict__ hb, int M) {
  __shared__ short As[128][40];
  __shared__ short Bs[64][264];
  const int t = threadIdx.x;
  const int brow = blockIdx.x * 128;
  const int w = t >> 6;
  const int l = t & 63;
  const int mlane = l & 15;
  const int quad = l >> 4;

  for (int i = 0; i < 64; ++i) {
    const int flat = i * 256 + t;
    const int k = flat >> 6, n = flat & 63;
    Bs[n][k] = (short)f2bf(W[flat]);
  }

  f4_t acc[2][4];
#pragma unroll
  for (int a = 0; a < 2; ++a)
#pragma unroll
    for (int b = 0; b < 4; ++b) acc[a][b] = (f4_t){0.f, 0.f, 0.f, 0.f};

  for (int k0 = 0; k0 < F_IN; k0 += 32) {
    {
      const int q = t & 7;
      const int rbase = t >> 3;
#pragma unroll
      for (int j = 0; j < 4; ++j) {
        const int r = rbase + j * 32;
        const int row = brow + r;
        float4 v = make_float4(0.f, 0.f, 0.f, 0.f);
        if (row < M) v = *(const float4*)(x + (size_t)row * F_IN + k0 + (q << 2));
        short* p = &As[r][q << 2];
        p[0] = (short)f2bf(v.x);
        p[1] = (short)f2bf(v.y);
        p[2] = (short)f2bf(v.z);
        p[3] = (short)f2bf(v.w);
      }
    }
    __syncthreads();
    bf8_t afr[2], bfr[4];
#pragma unroll
    for (int mt = 0; mt < 2; ++mt)
      afr[mt] = *(const bf8_t*)&As[w * 32 + mt * 16 + mlane][quad << 3];
#pragma unroll
    for (int nt = 0; nt < 4; ++nt)
      bfr[nt] = *(const bf8_t*)&Bs[nt * 16 + mlane][k0 + (quad << 3)];
#pragma unroll
    for (int mt = 0; mt < 2; ++mt)
#pragma unroll
      for (int nt = 0; nt < 4; ++nt)
        acc[mt][nt] = __builtin_amdgcn_mfma_f32_16x16x32_bf16(
            afr[mt], bfr[nt], acc[mt][nt], 0, 0, 0);
    __syncthreads();
  }

#pragma unroll
  for (int mt = 0; mt < 2; ++mt) {
#pragma unroll
    for (int reg = 0; reg < 4; ++reg) {
      const int row = brow + w * 32 + mt * 16 + (quad << 2) + reg;
      if (row < M) {
        const float di = dinvp[row];
#pragma unroll
        for (int nt = 0; nt < 4; ++nt)
          hb[(size_t)row * 64 + nt * 16 + mlane] = f2bf(di * acc[mt][nt][reg]);
      }
    }
  }
}

// ------- block-local sort: each chunk sorted by bucket into own region -------
__global__ __launch_bounds__(512) void sort_local_kernel(
    const int* __restrict__ src_arr, const int* __restrict__ dst_arr,
    int* __restrict__ espB, int* __restrict__ segStart, int* __restrict__ segCnt,
    int* __restrict__ bucketCount, int E, int NBK) {
  __shared__ int hist[512];
  __shared__ int s[512];
  __shared__ int cur[512];
  const int t = threadIdx.x;
  const int blk = blockIdx.x;
  const int base = blk * CHUNK;
  const int cnt = min(CHUNK, E - base);
  for (int i = t; i < NBK; i += 512) hist[i] = 0;
  __syncthreads();
  int pk[16], bk[16];
#pragma unroll
  for (int k = 0; k < 16; ++k) {
    const int i = t + k * 512;
    bk[k] = -1;
    if (i < cnt) {
      const int sv = src_arr[base + i];
      const int dv = dst_arr[base + i];
      pk[k] = sv | ((dv & 255) << 24);
      bk[k] = dv >> 8;
      atomicAdd(&hist[bk[k]], 1);
    }
  }
  __syncthreads();
  const int v = (t < NBK) ? hist[t] : 0;
  s[t] = v;
  __syncthreads();
#pragma unroll
  for (int off = 1; off < 512; off <<= 1) {
    int add = (t >= off) ? s[t - off] : 0;
    __syncthreads();
    s[t] += add;
    __syncthreads();
  }
  if (t < NBK) {
    const int excl = s[t] - v;
    cur[t] = excl;
    segStart[blk * NBK + t] = base + excl;   // block-major: dense writes
    segCnt[blk * NBK + t] = v;
    if (v) atomicAdd(&bucketCount[t], v);
  }
  __syncthreads();
#pragma unroll
  for (int k = 0; k < 16; ++k) {
    if (bk[k] >= 0) {
      const int pos = atomicAdd(&cur[bk[k]], 1);
      espB[base + pos] = pk[k];              // dense 32 KB streaming write
    }
  }
}

// ---------------- scan bucket counts (NBK <= 512) ----------------------------
__global__ __launch_bounds__(512) void scan_buckets_kernel(
    const int* __restrict__ bucketCount, int* __restrict__ bucketStart, int NBK) {
  __shared__ int s[512];
  const int t = threadIdx.x;
  const int v = (t < NBK) ? bucketCount[t] : 0;
  s[t] = v;
  __syncthreads();
#pragma unroll
  for (int off = 1; off < 512; off <<= 1) {
    int add = (t >= off) ? s[t - off] : 0;
    __syncthreads();
    s[t] += add;
    __syncthreads();
  }
  if (t < NBK) bucketStart[t] = s[t] - v;
  if (t == NBK - 1) bucketStart[NBK] = s[t];
}

// ------ per-bucket fine bin: segment-wise walk (no binary search) ------------
__global__ __launch_bounds__(512) void fine_bin2_kernel(
    const int* __restrict__ espB, const int* __restrict__ segStart,
    const int* __restrict__ segCnt, const int* __restrict__ bucketStart,
    int* __restrict__ es, int* __restrict__ rowptr, float* __restrict__ dinvp,
    int N, int E, int NBK, int NCH) {
  __shared__ int segS[512];
  __shared__ int segC[512];
  __shared__ int sbuf[512];
  __shared__ int hist[256];
  __shared__ int cur[256];
  const int t = threadIdx.x;
  const int b = blockIdx.x;
  for (int i = t; i < 512; i += 512) { segS[i] = 0; segC[i] = 0; }
  if (t < 256) hist[t] = 0;
  __syncthreads();
  for (int i = t; i < NCH; i += 512) {
    segS[i] = segStart[i * NBK + b];
    segC[i] = segCnt[i * NBK + b];
  }
  __syncthreads();

  const int wid = t >> 6;
  const int lane = t & 63;

  // pass 1: per-node histogram
  for (int seg = wid; seg < NCH; seg += 8) {
    const int sS = segS[seg], c = segC[seg];
    for (int j = lane; j < c; j += 64)
      atomicAdd(&hist[((unsigned)espB[sS + j]) >> 24], 1);
  }
  __syncthreads();

  // scan 256 bins
  int v2 = 0;
  if (t < 256) { v2 = hist[t]; sbuf[t] = v2; }
  __syncthreads();
#pragma unroll
  for (int off = 1; off < 256; off <<= 1) {
    int add = 0;
    if (t < 256 && t >= off) add = sbuf[t - off];
    __syncthreads();
    if (t < 256) sbuf[t] += add;
    __syncthreads();
  }
  const int base = bucketStart[b];
  if (t < 256) {
    const int excl = sbuf[t] - v2;
    cur[t] = base + excl;
    const int node = b * 256 + t;
    if (node < N) {
      rowptr[node] = base + excl;
      dinvp[node] = rsqrtf((float)(v2 + 1));  // +1 self-loop
    }
  }
  if (b == 0 && t == 0) rowptr[N] = E;
  __syncthreads();

  // pass 2: scatter into this bucket's CSR window
  for (int seg = wid; seg < NCH; seg += 8) {
    const int sS = segS[seg], c = segC[seg];
    for (int j = lane; j < c; j += 64) {
      const int p = espB[sS + j];
      const int pos = atomicAdd(&cur[((unsigned)p) >> 24], 1);
      es[pos] = p & 0x00FFFFFF;
    }
  }
}

// ------- CSR aggregation: one wave per node, bf16 pre-scaled gather ----------
__global__ __launch_bounds__(256) void agg_csr_kernel(
    const unsigned short* __restrict__ hb, const int* __restrict__ es,
    const int* __restrict__ rowptr, const float* __restrict__ dinvp,
    float* __restrict__ agg, int N) {
  const int t = threadIdx.x;
  const int node = blockIdx.x * 4 + (t >> 6);
  if (node >= N) return;
  const int lane = t & 63;
  const int slot = lane >> 3;
  const int fq = (lane & 7) << 3;
  const int start = rowptr[node];
  const int end = rowptr[node + 1];

  float acc[8] = {0.f};
  int i = start + slot;
  for (; i + 8 < end; i += 16) {
    const int s0 = es[i];
    const int s1 = es[i + 8];
    const uint4 r0 = *(const uint4*)(hb + (size_t)s0 * 64 + fq);
    const uint4 r1 = *(const uint4*)(hb + (size_t)s1 * 64 + fq);
    acc[0] += BF_LO(r0.x) + BF_LO(r1.x);
    acc[1] += BF_HI(r0.x) + BF_HI(r1.x);
    acc[2] += BF_LO(r0.y) + BF_LO(r1.y);
    acc[3] += BF_HI(r0.y) + BF_HI(r1.y);
    acc[4] += BF_LO(r0.z) + BF_LO(r1.z);
    acc[5] += BF_HI(r0.z) + BF_HI(r1.z);
    acc[6] += BF_LO(r0.w) + BF_LO(r1.w);
    acc[7] += BF_HI(r0.w) + BF_HI(r1.w);
  }
  if (i < end) {
    const int s0 = es[i];
    const uint4 r0 = *(const uint4*)(hb + (size_t)s0 * 64 + fq);
    acc[0] += BF_LO(r0.x);
    acc[1] += BF_HI(r0.x);
    acc[2] += BF_LO(r0.y);
    acc[3] += BF_HI(r0.y);
    acc[4] += BF_LO(r0.z);
    acc[5] += BF_HI(r0.z);
    acc[6] += BF_LO(r0.w);
    acc[7] += BF_HI(r0.w);
  }
#pragma unroll
  for (int m = 8; m <= 32; m <<= 1)
#pragma unroll
    for (int j = 0; j < 8; ++j) acc[j] += __shfl_xor(acc[j], m, 64);

  if (slot == 0) {
    const float di = dinvp[node];
    float4 o0 = make_float4(acc[0] * di, acc[1] * di, acc[2] * di, acc[3] * di);
    float4 o1 = make_float4(acc[4] * di, acc[5] * di, acc[6] * di, acc[7] * di);
    float* ap = agg + (size_t)node * 64 + fq;
    *(float4*)(ap + 0) = o0;
    *(float4*)(ap + 4) = o1;
  }
}

// ---------------- MFMA MLP: 256 nodes/block, 3 layers in LDS -----------------
__global__ __launch_bounds__(256) void mlp_mfma_kernel(
    const float* __restrict__ agg, const unsigned short* __restrict__ hb,
    const float* __restrict__ dinvp, const float* __restrict__ bg,
    const float* __restrict__ W1, const float* __restrict__ b1,
    const float* __restrict__ W2, const float* __restrict__ b2,
    const float* __restrict__ W3, const float* __restrict__ b3,
    float* __restrict__ out, int N) {
  __shared__ short g64[256 * 72];   // [node][feat] bf16, stride 72 (h1 aliases)
  __shared__ short h2s[256 * 40];   // [node][feat] bf16, cols 16..31 zero
  __shared__ short W1s[32 * 72];    // [n][k] k<64
  __shared__ short W2s[16 * 40];    // [n][k] k<32
  __shared__ short W3s[16 * 40];    // [n][k] k<16, rest zero
  __shared__ float bgs[64], b1s[32], b2s[16], b3s[16];
  short* h1s = g64;                 // [node][feat] stride 40, alias after layer1

  const int t = threadIdx.x;
  const int node0 = blockIdx.x * 256;
  // phase 0: zeros + biases
  for (int i = t; i < 256 * 40; i += 256) h2s[i] = 0;
  for (int i = t; i < 16 * 40; i += 256) W3s[i] = 0;
  if (t < 64) bgs[t] = bg[t];
  if (t < 32) b1s[t] = b1[t];
  if (t < 16) { b2s[t] = b2[t]; b3s[t] = (t < 10) ? b3[t] : 0.f; }
  __syncthreads();
  // phase 1: weights + g staging
  for (int i = t; i < 2048; i += 256) { const int k = i >> 5, n = i & 31; W1s[n * 72 + k] = (short)f2bf(W1[i]); }
  for (int i = t; i < 512;  i += 256) { const int k = i >> 4, n = i & 15; W2s[n * 40 + k] = (short)f2bf(W2[i]); }
  if (t < 160) { const int k = t / 10, n = t % 10; W3s[n * 40 + k] = (short)f2bf(W3[t]); }
  {
    const int nd = min(node0 + t, N - 1);
    const float di = dinvp[nd];
    short* gr = &g64[t * 72];
    const float* ar = agg + (size_t)nd * 64;
    const unsigned short* hr = hb + (size_t)nd * 64;
#pragma unroll
    for (int k = 0; k < 64; k += 8) {
      const float4 a0 = *(const float4*)(ar + k);
      const float4 a1 = *(const float4*)(ar + k + 4);
      const uint4 r = *(const uint4*)(hr + k);
      gr[k + 0] = (short)f2bf(fmaxf(a0.x + di * BF_LO(r.x) + bgs[k + 0], 0.f));
      gr[k + 1] = (short)f2bf(fmaxf(a0.y + di * BF_HI(r.x) + bgs[k + 1], 0.f));
      gr[k + 2] = (short)f2bf(fmaxf(a0.z + di * BF_LO(r.y) + bgs[k + 2], 0.f));
      gr[k + 3] = (short)f2bf(fmaxf(a0.w + di * BF_HI(r.y) + bgs[k + 3], 0.f));
      gr[k + 4] = (short)f2bf(fmaxf(a1.x + di * BF_LO(r.z) + bgs[k + 4], 0.f));
      gr[k + 5] = (short)f2bf(fmaxf(a1.y + di * BF_HI(r.z) + bgs[k + 5], 0.f));
      gr[k + 6] = (short)f2bf(fmaxf(a1.z + di * BF_LO(r.w) + bgs[k + 6], 0.f));
      gr[k + 7] = (short)f2bf(fmaxf(a1.w + di * BF_HI(r.w) + bgs[k + 7], 0.f));
    }
  }
  __syncthreads();

  const int w = t >> 6;
  const int lane = t & 63;
  const int ml = lane & 15;
  const int quad = lane >> 4;

  // layer 1: (256x64) @ (64x32)
  bf8_t a1f[4][2], b1f[2][2];
#pragma unroll
  for (int mt = 0; mt < 4; ++mt)
#pragma unroll
    for (int ks = 0; ks < 2; ++ks)
      a1f[mt][ks] = *(const bf8_t*)&g64[(w * 64 + mt * 16 + ml) * 72 + ks * 32 + quad * 8];
#pragma unroll
  for (int nt = 0; nt < 2; ++nt)
#pragma unroll
    for (int ks = 0; ks < 2; ++ks)
      b1f[nt][ks] = *(const bf8_t*)&W1s[(nt * 16 + ml) * 72 + ks * 32 + quad * 8];
  f4_t acc1[4][2];
#pragma unroll
  for (int mt = 0; mt < 4; ++mt)
#pragma unroll
    for (int nt = 0; nt < 2; ++nt) acc1[mt][nt] = (f4_t){0.f, 0.f, 0.f, 0.f};
#pragma unroll
  for (int ks = 0; ks < 2; ++ks)
#pragma unroll
    for (int mt = 0; mt < 4; ++mt)
#pragma unroll
      for (int nt = 0; nt < 2; ++nt)
        acc1[mt][nt] = __builtin_amdgcn_mfma_f32_16x16x32_bf16(
            a1f[mt][ks], b1f[nt][ks], acc1[mt][nt], 0, 0, 0);
  __syncthreads();  // all g64 reads done before h1 alias writes
#pragma unroll
  for (int mt = 0; mt < 4; ++mt)
#pragma unroll
    for (int nt = 0; nt < 2; ++nt)
#pragma unroll
      for (int reg = 0; reg < 4; ++reg) {
        const int row = w * 64 + mt * 16 + quad * 4 + reg;
        const int col = nt * 16 + ml;
        h1s[row * 40 + col] = (short)f2bf(fmaxf(acc1[mt][nt][reg] + b1s[col], 0.f));
      }
  __syncthreads();

  // layer 2: (256x32) @ (32x16)
  bf8_t a2f[4];
#pragma unroll
  for (int mt = 0; mt < 4; ++mt)
    a2f[mt] = *(const bf8_t*)&h1s[(w * 64 + mt * 16 + ml) * 40 + quad * 8];
  const bf8_t b2f = *(const bf8_t*)&W2s[ml * 40 + quad * 8];
  f4_t acc2[4];
#pragma unroll
  for (int mt = 0; mt < 4; ++mt) {
    acc2[mt] = (f4_t){0.f, 0.f, 0.f, 0.f};
    acc2[mt] = __builtin_amdgcn_mfma_f32_16x16x32_bf16(a2f[mt], b2f, acc2[mt], 0, 0, 0);
  }
  __syncthreads();
#pragma unroll
  for (int mt = 0; mt < 4; ++mt)
#pragma unroll
    for (int reg = 0; reg < 4; ++reg) {
      const int row = w * 64 + mt * 16 + quad * 4 + reg;
      h2s[row * 40 + ml] = (short)f2bf(fmaxf(acc2[mt][reg] + b2s[ml], 0.f));
    }
  __syncthreads();

  // layer 3: (256x16) @ (16x10), K zero-padded to 32
  bf8_t a3f[4];
#pragma unroll
  for (int mt = 0; mt < 4; ++mt)
    a3f[mt] = *(const bf8_t*)&h2s[(w * 64 + mt * 16 + ml) * 40 + quad * 8];
  const bf8_t b3f = *(const bf8_t*)&W3s[ml * 40 + quad * 8];
#pragma unroll
  for (int mt = 0; mt < 4; ++mt) {
    f4_t acc3 = (f4_t){0.f, 0.f, 0.f, 0.f};
    acc3 = __builtin_amdgcn_mfma_f32_16x16x32_bf16(a3f[mt], b3f, acc3, 0, 0, 0);
#pragma unroll
    for (int reg = 0; reg < 4; ++reg) {
      const int node = node0 + w * 64 + mt * 16 + quad * 4 + reg;
      if (ml < 10 && node < N) out[(size_t)node * 10 + ml] = acc3[reg] + b3s[ml];
    }
  }
}

extern "C" void kernel_launch(void* const* d_in, const int* in_sizes, int n_in,
                              void* d_out, int out_size, void* d_ws, size_t ws_size,
                              hipStream_t stream) {
  const float* x     = (const float*)d_in[0];
  const int*   ei    = (const int*)d_in[1];
  const float* W_gcn = (const float*)d_in[2];
  const float* b_gcn = (const float*)d_in[3];
  const float* W1    = (const float*)d_in[4];
  const float* b1    = (const float*)d_in[5];
  const float* W2    = (const float*)d_in[6];
  const float* b2    = (const float*)d_in[7];
  const float* W3    = (const float*)d_in[8];
  const float* b3    = (const float*)d_in[9];
  float* out = (float*)d_out;

  const int N = in_sizes[0] / F_IN;   // 100000
  const int E = in_sizes[1] / 2;      // 3200000
  const int* src = ei;
  const int* dst = ei + E;
  const int NBK = (N + 255) >> 8;     // 391 buckets of 256 nodes
  const int NCH = (E + CHUNK - 1) / CHUNK;  // 391 chunks

  // Layout: espB/segStart/segCnt dead after fine_bin2 -> aliased by agg.
  unsigned short* hb = (unsigned short*)d_ws;            // N*64 us  (12.8 MB)
  float* dinvp       = (float*)(hb + (size_t)N * 64);    // N f
  int*   es          = (int*)(dinvp + N);                // E i      (12.8 MB)
  int*   rowptr      = es + E;                           // N+16 i
  int*   bucketCount = rowptr + N + 16;                  // 512 i
  int*   bucketStart = bucketCount + 512;                // 528 i
  int*   espB        = bucketStart + 528;                // E i      (12.8 MB)
  int*   segStart    = espB + E;                         // NCH*NBK i (0.61 MB)
  int*   segCnt      = segStart + NCH * NBK;             // NCH*NBK i (0.61 MB)
  float* agg         = (float*)espB;                     // N*64 f (25.6 MB alias)

  hipMemsetAsync(bucketCount, 0, 512 * sizeof(int), stream);

  sort_local_kernel<<<NCH, 512, 0, stream>>>(
      src, dst, espB, segStart, segCnt, bucketCount, E, NBK);
  scan_buckets_kernel<<<1, 512, 0, stream>>>(bucketCount, bucketStart, NBK);
  fine_bin2_kernel<<<NBK, 512, 0, stream>>>(
      espB, segStart, segCnt, bucketStart, es, rowptr, dinvp, N, E, NBK, NCH);

  gemm_mfma_kernel<<<(N + 127) / 128, 256, 0, stream>>>(x, W_gcn, dinvp, hb, N);

  agg_csr_kernel<<<(N + 3) / 4, 256, 0, stream>>>(hb, es, rowptr, dinvp, agg, N);

  mlp_mfma_kernel<<<(N + 255) / 256, 256, 0, stream>>>(
      agg, hb, dinvp, b_gcn, W1, b1, W2, b2, W3, b3, out, N);
}

// Round 9
// 342.249 us; speedup vs baseline: 1.2029x; 1.0530x over previous
//
#include <hip/hip_runtime.h>

#define F_IN 256
#define CHUNK 8192

typedef short bf8_t __attribute__((ext_vector_type(8)));   // 8 bf16
typedef float f4_t  __attribute__((ext_vector_type(4)));   // 4 fp32 acc

__device__ __forceinline__ unsigned short f2bf(float f) {
  unsigned u = __float_as_uint(f);
  unsigned r = (u + 0x7FFFu + ((u >> 16) & 1u)) >> 16;  // RNE
  return (unsigned short)r;
}
#define BF_LO(d) __uint_as_float((d) << 16)
#define BF_HI(d) __uint_as_float((d) & 0xFFFF0000u)

__device__ __forceinline__ bf8_t pack8(float4 a, float4 b) {
  bf8_t r;
  r[0] = (short)f2bf(a.x); r[1] = (short)f2bf(a.y);
  r[2] = (short)f2bf(a.z); r[3] = (short)f2bf(a.w);
  r[4] = (short)f2bf(b.x); r[5] = (short)f2bf(b.y);
  r[6] = (short)f2bf(b.z); r[7] = (short)f2bf(b.w);
  return r;
}

// ------- W prep: WbT[n][k] = bf16(W[k][n])  (one-time, 32 KB) ----------------
__global__ __launch_bounds__(256) void wprep_kernel(
    const float* __restrict__ W, unsigned short* __restrict__ WbT) {
  const int i = blockIdx.x * 256 + threadIdx.x;  // 0..16383
  const int k = i >> 6, n = i & 63;
  WbT[n * 256 + k] = f2bf(W[i]);
}

// ------- direct GEMM: hb = bf16(dinv[row]*(x @ W)); A from global, B in LDS --
__global__ __launch_bounds__(256) void gemm_direct_kernel(
    const float* __restrict__ x, const unsigned short* __restrict__ WbT,
    const float* __restrict__ dinvp, unsigned short* __restrict__ hb, int M) {
  __shared__ short Bs[64][264];   // [n][k], stride 264 (528 B) -> 2-way banks
  const int t = threadIdx.x;
  // stage WbT (32 KB) once, vectorized
  for (int i = t; i < 2048; i += 256) {
    const int n = i >> 5, kq = (i & 31) << 3;
    *(uint4*)&Bs[n][kq] = *(const uint4*)(WbT + n * 256 + kq);
  }
  __syncthreads();

  const int brow = blockIdx.x * 128;
  const int w = t >> 6;
  const int l = t & 63;
  const int ml = l & 15;
  const int quad = l >> 4;

  const int r0 = min(brow + w * 32 + ml, M - 1);
  const int r1 = min(brow + w * 32 + 16 + ml, M - 1);
  const float* xr0 = x + (size_t)r0 * F_IN + (quad << 3);
  const float* xr1 = x + (size_t)r1 * F_IN + (quad << 3);

  f4_t acc[2][4];
#pragma unroll
  for (int a = 0; a < 2; ++a)
#pragma unroll
    for (int b = 0; b < 4; ++b) acc[a][b] = (f4_t){0.f, 0.f, 0.f, 0.f};

#pragma unroll
  for (int k0 = 0; k0 < F_IN; k0 += 32) {
    bf8_t afr[2];
    {
      const float4 a0 = *(const float4*)(xr0 + k0);
      const float4 a1 = *(const float4*)(xr0 + k0 + 4);
      afr[0] = pack8(a0, a1);
      const float4 c0 = *(const float4*)(xr1 + k0);
      const float4 c1 = *(const float4*)(xr1 + k0 + 4);
      afr[1] = pack8(c0, c1);
    }
    bf8_t bfr[4];
#pragma unroll
    for (int nt = 0; nt < 4; ++nt)
      bfr[nt] = *(const bf8_t*)&Bs[nt * 16 + ml][k0 + (quad << 3)];
#pragma unroll
    for (int mt = 0; mt < 2; ++mt)
#pragma unroll
      for (int nt = 0; nt < 4; ++nt)
        acc[mt][nt] = __builtin_amdgcn_mfma_f32_16x16x32_bf16(
            afr[mt], bfr[nt], acc[mt][nt], 0, 0, 0);
  }

#pragma unroll
  for (int mt = 0; mt < 2; ++mt) {
#pragma unroll
    for (int reg = 0; reg < 4; ++reg) {
      const int row = brow + w * 32 + mt * 16 + (quad << 2) + reg;
      if (row < M) {
        const float di = dinvp[row];
#pragma unroll
        for (int nt = 0; nt < 4; ++nt)
          hb[(size_t)row * 64 + nt * 16 + ml] = f2bf(di * acc[mt][nt][reg]);
      }
    }
  }
}

// ------- block-local sort: each chunk sorted by bucket into own region -------
__global__ __launch_bounds__(512) void sort_local_kernel(
    const int* __restrict__ src_arr, const int* __restrict__ dst_arr,
    int* __restrict__ espB, int* __restrict__ segStart, int* __restrict__ segCnt,
    int* __restrict__ bucketCount, int E, int NBK) {
  __shared__ int hist[512];
  __shared__ int s[512];
  __shared__ int cur[512];
  const int t = threadIdx.x;
  const int blk = blockIdx.x;
  const int base = blk * CHUNK;
  const int cnt = min(CHUNK, E - base);
  for (int i = t; i < NBK; i += 512) hist[i] = 0;
  __syncthreads();
  int pk[16], bk[16];
#pragma unroll
  for (int k = 0; k < 16; ++k) {
    const int i = t + k * 512;
    bk[k] = -1;
    if (i < cnt) {
      const int sv = src_arr[base + i];
      const int dv = dst_arr[base + i];
      pk[k] = sv | ((dv & 255) << 24);
      bk[k] = dv >> 8;
      atomicAdd(&hist[bk[k]], 1);
    }
  }
  __syncthreads();
  const int v = (t < NBK) ? hist[t] : 0;
  s[t] = v;
  __syncthreads();
#pragma unroll
  for (int off = 1; off < 512; off <<= 1) {
    int add = (t >= off) ? s[t - off] : 0;
    __syncthreads();
    s[t] += add;
    __syncthreads();
  }
  if (t < NBK) {
    const int excl = s[t] - v;
    cur[t] = excl;
    segStart[blk * NBK + t] = base + excl;   // block-major: dense writes
    segCnt[blk * NBK + t] = v;
    if (v) atomicAdd(&bucketCount[t], v);
  }
  __syncthreads();
#pragma unroll
  for (int k = 0; k < 16; ++k) {
    if (bk[k] >= 0) {
      const int pos = atomicAdd(&cur[bk[k]], 1);
      espB[base + pos] = pk[k];              // dense 32 KB streaming write
    }
  }
}

// ---------------- scan bucket counts (NBK <= 512) ----------------------------
__global__ __launch_bounds__(512) void scan_buckets_kernel(
    const int* __restrict__ bucketCount, int* __restrict__ bucketStart, int NBK) {
  __shared__ int s[512];
  const int t = threadIdx.x;
  const int v = (t < NBK) ? bucketCount[t] : 0;
  s[t] = v;
  __syncthreads();
#pragma unroll
  for (int off = 1; off < 512; off <<= 1) {
    int add = (t >= off) ? s[t - off] : 0;
    __syncthreads();
    s[t] += add;
    __syncthreads();
  }
  if (t < NBK) bucketStart[t] = s[t] - v;
  if (t == NBK - 1) bucketStart[NBK] = s[t];
}

// ------ per-bucket fine bin: segment-wise walk (no binary search) ------------
__global__ __launch_bounds__(512) void fine_bin2_kernel(
    const int* __restrict__ espB, const int* __restrict__ segStart,
    const int* __restrict__ segCnt, const int* __restrict__ bucketStart,
    int* __restrict__ es, int* __restrict__ rowptr, float* __restrict__ dinvp,
    int N, int E, int NBK, int NCH) {
  __shared__ int segS[512];
  __shared__ int segC[512];
  __shared__ int sbuf[512];
  __shared__ int hist[256];
  __shared__ int cur[256];
  const int t = threadIdx.x;
  const int b = blockIdx.x;
  for (int i = t; i < 512; i += 512) { segS[i] = 0; segC[i] = 0; }
  if (t < 256) hist[t] = 0;
  __syncthreads();
  for (int i = t; i < NCH; i += 512) {
    segS[i] = segStart[i * NBK + b];
    segC[i] = segCnt[i * NBK + b];
  }
  __syncthreads();

  const int wid = t >> 6;
  const int lane = t & 63;

  // pass 1: per-node histogram
  for (int seg = wid; seg < NCH; seg += 8) {
    const int sS = segS[seg], c = segC[seg];
    for (int j = lane; j < c; j += 64)
      atomicAdd(&hist[((unsigned)espB[sS + j]) >> 24], 1);
  }
  __syncthreads();

  // scan 256 bins
  int v2 = 0;
  if (t < 256) { v2 = hist[t]; sbuf[t] = v2; }
  __syncthreads();
#pragma unroll
  for (int off = 1; off < 256; off <<= 1) {
    int add = 0;
    if (t < 256 && t >= off) add = sbuf[t - off];
    __syncthreads();
    if (t < 256) sbuf[t] += add;
    __syncthreads();
  }
  const int base = bucketStart[b];
  if (t < 256) {
    const int excl = sbuf[t] - v2;
    cur[t] = base + excl;
    const int node = b * 256 + t;
    if (node < N) {
      rowptr[node] = base + excl;
      dinvp[node] = rsqrtf((float)(v2 + 1));  // +1 self-loop
    }
  }
  if (b == 0 && t == 0) rowptr[N] = E;
  __syncthreads();

  // pass 2: scatter into this bucket's CSR window
  for (int seg = wid; seg < NCH; seg += 8) {
    const int sS = segS[seg], c = segC[seg];
    for (int j = lane; j < c; j += 64) {
      const int p = espB[sS + j];
      const int pos = atomicAdd(&cur[((unsigned)p) >> 24], 1);
      es[pos] = p & 0x00FFFFFF;
    }
  }
}

// ------- CSR aggregation: one wave per node, bf16 pre-scaled gather ----------
__global__ __launch_bounds__(256) void agg_csr_kernel(
    const unsigned short* __restrict__ hb, const int* __restrict__ es,
    const int* __restrict__ rowptr, const float* __restrict__ dinvp,
    float* __restrict__ agg, int N) {
  const int t = threadIdx.x;
  const int node = blockIdx.x * 4 + (t >> 6);
  if (node >= N) return;
  const int lane = t & 63;
  const int slot = lane >> 3;
  const int fq = (lane & 7) << 3;
  const int start = rowptr[node];
  const int end = rowptr[node + 1];

  float acc[8] = {0.f};
  int i = start + slot;
  for (; i + 8 < end; i += 16) {
    const int s0 = es[i];
    const int s1 = es[i + 8];
    const uint4 r0 = *(const uint4*)(hb + (size_t)s0 * 64 + fq);
    const uint4 r1 = *(const uint4*)(hb + (size_t)s1 * 64 + fq);
    acc[0] += BF_LO(r0.x) + BF_LO(r1.x);
    acc[1] += BF_HI(r0.x) + BF_HI(r1.x);
    acc[2] += BF_LO(r0.y) + BF_LO(r1.y);
    acc[3] += BF_HI(r0.y) + BF_HI(r1.y);
    acc[4] += BF_LO(r0.z) + BF_LO(r1.z);
    acc[5] += BF_HI(r0.z) + BF_HI(r1.z);
    acc[6] += BF_LO(r0.w) + BF_LO(r1.w);
    acc[7] += BF_HI(r0.w) + BF_HI(r1.w);
  }
  if (i < end) {
    const int s0 = es[i];
    const uint4 r0 = *(const uint4*)(hb + (size_t)s0 * 64 + fq);
    acc[0] += BF_LO(r0.x);
    acc[1] += BF_HI(r0.x);
    acc[2] += BF_LO(r0.y);
    acc[3] += BF_HI(r0.y);
    acc[4] += BF_LO(r0.z);
    acc[5] += BF_HI(r0.z);
    acc[6] += BF_LO(r0.w);
    acc[7] += BF_HI(r0.w);
  }
#pragma unroll
  for (int m = 8; m <= 32; m <<= 1)
#pragma unroll
    for (int j = 0; j < 8; ++j) acc[j] += __shfl_xor(acc[j], m, 64);

  if (slot == 0) {
    const float di = dinvp[node];
    float4 o0 = make_float4(acc[0] * di, acc[1] * di, acc[2] * di, acc[3] * di);
    float4 o1 = make_float4(acc[4] * di, acc[5] * di, acc[6] * di, acc[7] * di);
    float* ap = agg + (size_t)node * 64 + fq;
    *(float4*)(ap + 0) = o0;
    *(float4*)(ap + 4) = o1;
  }
}

// ---------------- MFMA MLP: 256 nodes/block, 3 layers in LDS -----------------
__global__ __launch_bounds__(256) void mlp_mfma_kernel(
    const float* __restrict__ agg, const unsigned short* __restrict__ hb,
    const float* __restrict__ dinvp, const float* __restrict__ bg,
    const float* __restrict__ W1, const float* __restrict__ b1,
    const float* __restrict__ W2, const float* __restrict__ b2,
    const float* __restrict__ W3, const float* __restrict__ b3,
    float* __restrict__ out, int N) {
  __shared__ short g64[256 * 72];   // [node][feat] bf16, stride 72 (h1 aliases)
  __shared__ short h2s[256 * 40];   // [node][feat] bf16, cols 16..31 zero
  __shared__ short W1s[32 * 72];    // [n][k] k<64
  __shared__ short W2s[16 * 40];    // [n][k] k<32
  __shared__ short W3s[16 * 40];    // [n][k] k<16, rest zero
  __shared__ float bgs[64], b1s[32], b2s[16], b3s[16];
  short* h1s = g64;                 // [node][feat] stride 40, alias after layer1

  const int t = threadIdx.x;
  const int node0 = blockIdx.x * 256;
  for (int i = t; i < 256 * 40; i += 256) h2s[i] = 0;
  for (int i = t; i < 16 * 40; i += 256) W3s[i] = 0;
  if (t < 64) bgs[t] = bg[t];
  if (t < 32) b1s[t] = b1[t];
  if (t < 16) { b2s[t] = b2[t]; b3s[t] = (t < 10) ? b3[t] : 0.f; }
  __syncthreads();
  for (int i = t; i < 2048; i += 256) { const int k = i >> 5, n = i & 31; W1s[n * 72 + k] = (short)f2bf(W1[i]); }
  for (int i = t; i < 512;  i += 256) { const int k = i >> 4, n = i & 15; W2s[n * 40 + k] = (short)f2bf(W2[i]); }
  if (t < 160) { const int k = t / 10, n = t % 10; W3s[n * 40 + k] = (short)f2bf(W3[t]); }
  {
    const int nd = min(node0 + t, N - 1);
    const float di = dinvp[nd];
    short* gr = &g64[t * 72];
    const float* ar = agg + (size_t)nd * 64;
    const unsigned short* hr = hb + (size_t)nd * 64;
#pragma unroll
    for (int k = 0; k < 64; k += 8) {
      const float4 a0 = *(const float4*)(ar + k);
      const float4 a1 = *(const float4*)(ar + k + 4);
      const uint4 r = *(const uint4*)(hr + k);
      gr[k + 0] = (short)f2bf(fmaxf(a0.x + di * BF_LO(r.x) + bgs[k + 0], 0.f));
      gr[k + 1] = (short)f2bf(fmaxf(a0.y + di * BF_HI(r.x) + bgs[k + 1], 0.f));
      gr[k + 2] = (short)f2bf(fmaxf(a0.z + di * BF_LO(r.y) + bgs[k + 2], 0.f));
      gr[k + 3] = (short)f2bf(fmaxf(a0.w + di * BF_HI(r.y) + bgs[k + 3], 0.f));
      gr[k + 4] = (short)f2bf(fmaxf(a1.x + di * BF_LO(r.z) + bgs[k + 4], 0.f));
      gr[k + 5] = (short)f2bf(fmaxf(a1.y + di * BF_HI(r.z) + bgs[k + 5], 0.f));
      gr[k + 6] = (short)f2bf(fmaxf(a1.z + di * BF_LO(r.w) + bgs[k + 6], 0.f));
      gr[k + 7] = (short)f2bf(fmaxf(a1.w + di * BF_HI(r.w) + bgs[k + 7], 0.f));
    }
  }
  __syncthreads();

  const int w = t >> 6;
  const int lane = t & 63;
  const int ml = lane & 15;
  const int quad = lane >> 4;

  // layer 1: (256x64) @ (64x32)
  bf8_t a1f[4][2], b1f[2][2];
#pragma unroll
  for (int mt = 0; mt < 4; ++mt)
#pragma unroll
    for (int ks = 0; ks < 2; ++ks)
      a1f[mt][ks] = *(const bf8_t*)&g64[(w * 64 + mt * 16 + ml) * 72 + ks * 32 + quad * 8];
#pragma unroll
  for (int nt = 0; nt < 2; ++nt)
#pragma unroll
    for (int ks = 0; ks < 2; ++ks)
      b1f[nt][ks] = *(const bf8_t*)&W1s[(nt * 16 + ml) * 72 + ks * 32 + quad * 8];
  f4_t acc1[4][2];
#pragma unroll
  for (int mt = 0; mt < 4; ++mt)
#pragma unroll
    for (int nt = 0; nt < 2; ++nt) acc1[mt][nt] = (f4_t){0.f, 0.f, 0.f, 0.f};
#pragma unroll
  for (int ks = 0; ks < 2; ++ks)
#pragma unroll
    for (int mt = 0; mt < 4; ++mt)
#pragma unroll
      for (int nt = 0; nt < 2; ++nt)
        acc1[mt][nt] = __builtin_amdgcn_mfma_f32_16x16x32_bf16(
            a1f[mt][ks], b1f[nt][ks], acc1[mt][nt], 0, 0, 0);
  __syncthreads();
#pragma unroll
  for (int mt = 0; mt < 4; ++mt)
#pragma unroll
    for (int nt = 0; nt < 2; ++nt)
#pragma unroll
      for (int reg = 0; reg < 4; ++reg) {
        const int row = w * 64 + mt * 16 + quad * 4 + reg;
        const int col = nt * 16 + ml;
        h1s[row * 40 + col] = (short)f2bf(fmaxf(acc1[mt][nt][reg] + b1s[col], 0.f));
      }
  __syncthreads();

  // layer 2: (256x32) @ (32x16)
  bf8_t a2f[4];
#pragma unroll
  for (int mt = 0; mt < 4; ++mt)
    a2f[mt] = *(const bf8_t*)&h1s[(w * 64 + mt * 16 + ml) * 40 + quad * 8];
  const bf8_t b2f = *(const bf8_t*)&W2s[ml * 40 + quad * 8];
  f4_t acc2[4];
#pragma unroll
  for (int mt = 0; mt < 4; ++mt) {
    acc2[mt] = (f4_t){0.f, 0.f, 0.f, 0.f};
    acc2[mt] = __builtin_amdgcn_mfma_f32_16x16x32_bf16(a2f[mt], b2f, acc2[mt], 0, 0, 0);
  }
  __syncthreads();
#pragma unroll
  for (int mt = 0; mt < 4; ++mt)
#pragma unroll
    for (int reg = 0; reg < 4; ++reg) {
      const int row = w * 64 + mt * 16 + quad * 4 + reg;
      h2s[row * 40 + ml] = (short)f2bf(fmaxf(acc2[mt][reg] + b2s[ml], 0.f));
    }
  __syncthreads();

  // layer 3: (256x16) @ (16x10), K zero-padded to 32
  bf8_t a3f[4];
#pragma unroll
  for (int mt = 0; mt < 4; ++mt)
    a3f[mt] = *(const bf8_t*)&h2s[(w * 64 + mt * 16 + ml) * 40 + quad * 8];
  const bf8_t b3f = *(const bf8_t*)&W3s[ml * 40 + quad * 8];
#pragma unroll
  for (int mt = 0; mt < 4; ++mt) {
    f4_t acc3 = (f4_t){0.f, 0.f, 0.f, 0.f};
    acc3 = __builtin_amdgcn_mfma_f32_16x16x32_bf16(a3f[mt], b3f, acc3, 0, 0, 0);
#pragma unroll
    for (int reg = 0; reg < 4; ++reg) {
      const int node = node0 + w * 64 + mt * 16 + quad * 4 + reg;
      if (ml < 10 && node < N) out[(size_t)node * 10 + ml] = acc3[reg] + b3s[ml];
    }
  }
}

extern "C" void kernel_launch(void* const* d_in, const int* in_sizes, int n_in,
                              void* d_out, int out_size, void* d_ws, size_t ws_size,
                              hipStream_t stream) {
  const float* x     = (const float*)d_in[0];
  const int*   ei    = (const int*)d_in[1];
  const float* W_gcn = (const float*)d_in[2];
  const float* b_gcn = (const float*)d_in[3];
  const float* W1    = (const float*)d_in[4];
  const float* b1    = (const float*)d_in[5];
  const float* W2    = (const float*)d_in[6];
  const float* b2    = (const float*)d_in[7];
  const float* W3    = (const float*)d_in[8];
  const float* b3    = (const float*)d_in[9];
  float* out = (float*)d_out;

  const int N = in_sizes[0] / F_IN;   // 100000
  const int E = in_sizes[1] / 2;      // 3200000
  const int* src = ei;
  const int* dst = ei + E;
  const int NBK = (N + 255) >> 8;     // 391 buckets of 256 nodes
  const int NCH = (E + CHUNK - 1) / CHUNK;  // 391 chunks

  // Layout: espB/segStart/segCnt/WbT dead before agg writes -> aliased by agg.
  unsigned short* hb = (unsigned short*)d_ws;            // N*64 us  (12.8 MB)
  float* dinvp       = (float*)(hb + (size_t)N * 64);    // N f
  int*   es          = (int*)(dinvp + N);                // E i      (12.8 MB)
  int*   rowptr      = es + E;                           // N+16 i
  int*   bucketCount = rowptr + N + 16;                  // 512 i
  int*   bucketStart = bucketCount + 512;                // 528 i
  int*   espB        = bucketStart + 528;                // E i      (12.8 MB)
  int*   segStart    = espB + E;                         // NCH*NBK i (0.61 MB)
  int*   segCnt      = segStart + NCH * NBK;             // NCH*NBK i (0.61 MB)
  unsigned short* WbT= (unsigned short*)(segCnt + NCH * NBK); // 16384 us (32 KB)
  float* agg         = (float*)espB;                     // N*64 f (25.6 MB alias)

  hipMemsetAsync(bucketCount, 0, 512 * sizeof(int), stream);

  wprep_kernel<<<64, 256, 0, stream>>>(W_gcn, WbT);
  sort_local_kernel<<<NCH, 512, 0, stream>>>(
      src, dst, espB, segStart, segCnt, bucketCount, E, NBK);
  scan_buckets_kernel<<<1, 512, 0, stream>>>(bucketCount, bucketStart, NBK);
  fine_bin2_kernel<<<NBK, 512, 0, stream>>>(
      espB, segStart, segCnt, bucketStart, es, rowptr, dinvp, N, E, NBK, NCH);

  gemm_direct_kernel<<<(N + 127) / 128, 256, 0, stream>>>(x, WbT, dinvp, hb, N);

  agg_csr_kernel<<<(N + 3) / 4, 256, 0, stream>>>(hb, es, rowptr, dinvp, agg, N);

  mlp_mfma_kernel<<<(N + 255) / 256, 256, 0, stream>>>(
      agg, hb, dinvp, b_gcn, W1, b1, W2, b2, W3, b3, out, N);
}